// Round 8
// baseline (1477.746 us; speedup 1.0000x reference)
//
#include <hip/hip_runtime.h>
#include <hip/hip_bf16.h>
#include <stdint.h>
#include <stddef.h>

typedef __bf16 bf16;
typedef __bf16 v8bf __attribute__((ext_vector_type(8)));
typedef float  v4f  __attribute__((ext_vector_type(4)));

#define B_ 512
#define T_ 128
#define I_ 512
#define H_ 512
#define C_ 97
#define S_ 26

// ---------------------------------------------------------------- helpers
__device__ __forceinline__ void async_copy16(void* lds, const void* g) {
  __builtin_amdgcn_global_load_lds((__attribute__((address_space(1))) void*)g,
                                   (__attribute__((address_space(3))) void*)lds,
                                   16, 0, 0);
}

__device__ __forceinline__ float fast_tanh(float x) {
  float e = __expf(2.0f * x);
  return fmaf(-2.0f, __builtin_amdgcn_rcpf(e + 1.0f), 1.0f);
}
__device__ __forceinline__ float fast_sigmoid(float x) {
  float t = __expf(-x);
  return __builtin_amdgcn_rcpf(1.0f + t);
}

__device__ __forceinline__ void zero_acc(v4f acc[4][4]) {
  v4f z = {0.f, 0.f, 0.f, 0.f};
#pragma unroll
  for (int i = 0; i < 4; ++i)
#pragma unroll
    for (int j = 0; j < 4; ++j) acc[i][j] = z;
}

// packed bf16 stores (hipcc won't vectorize scalar bf16 stores)
__device__ __forceinline__ void store_bf16x8(bf16* dst, v4f a, v4f b) {
  union { bf16 h[8]; uint4 u; } pk;
#pragma unroll
  for (int j = 0; j < 4; ++j) { pk.h[j] = (bf16)a[j]; pk.h[4 + j] = (bf16)b[j]; }
  *(uint4*)dst = pk.u;
}
__device__ __forceinline__ void store_bf16x4(bf16* dst, float a0, float a1,
                                             float a2, float a3) {
  union { bf16 h[4]; uint2 u; } pk;
  pk.h[0] = (bf16)a0; pk.h[1] = (bf16)a1; pk.h[2] = (bf16)a2; pk.h[3] = (bf16)a3;
  *(uint2*)dst = pk.u;
}

// T3/T4 sync primitive: counted vmcnt (never 0 mid-loop) + raw barrier.
#define WAITBAR(N)                                             \
  do {                                                         \
    asm volatile("s_waitcnt vmcnt(" #N ")" ::: "memory");      \
    __builtin_amdgcn_s_barrier();                              \
    __builtin_amdgcn_sched_barrier(0);                         \
  } while (0)

// ---------------- 128x128 tile, BK=32, quad-buffer depth-2 prefetch
template <int KTOT>
__device__ __forceinline__ void mm_qb32(const bf16* aRow0, const bf16* aRow1,
                                        const bf16* bRow0, const bf16* bRow1,
                                        bf16* As, bf16* Bs, int tid,
                                        v4f acc[4][4]) {
  constexpr int NT = KTOT / 32;  // >= 3
  const int wave = tid >> 6, lane = tid & 63;
  const int wr = (wave >> 1) * 64, wc = (wave & 1) * 64;
  const int fr = lane & 15, fq = lane >> 4;
  const int s0 = tid * 8;
  const int aB = (wr + fr) * 32 + fq * 8;
  const int bB = (wc + fr) * 32 + fq * 8;
#define STG32(bi, kk)                                   \
  do {                                                  \
    const int o = (bi) * 4096 + s0;                     \
    async_copy16(As + o, aRow0 + (kk));                 \
    async_copy16(As + o + 2048, aRow1 + (kk));          \
    async_copy16(Bs + o, bRow0 + (kk));                 \
    async_copy16(Bs + o + 2048, bRow1 + (kk));          \
  } while (0)
  STG32(0, 0);
  STG32(1, 32);
  for (int t = 0; t < NT; ++t) {
    if (t + 2 < NT) {
      STG32((t + 2) & 3, (t + 2) * 32);
      WAITBAR(8);
    } else if (t + 1 < NT) {
      WAITBAR(4);
    } else {
      WAITBAR(0);
    }
    const int cb = (t & 3) * 4096;
    v8bf av[4], bv[4];
#pragma unroll
    for (int i = 0; i < 4; ++i) av[i] = *(const v8bf*)(As + cb + aB + i * 512);
#pragma unroll
    for (int j = 0; j < 4; ++j) bv[j] = *(const v8bf*)(Bs + cb + bB + j * 512);
    __builtin_amdgcn_s_setprio(1);
#pragma unroll
    for (int i = 0; i < 4; ++i) {
#pragma unroll
      for (int j = 0; j < 4; ++j) {
        acc[i][j] = __builtin_amdgcn_mfma_f32_16x16x32_bf16(av[i], bv[j], acc[i][j], 0, 0, 0);
      }
    }
    __builtin_amdgcn_s_setprio(0);
  }
#undef STG32
}

// ---------------------- fallback 128x128 mainloop (fp32 A, register staging)
template <int KTOT>
__device__ __forceinline__ void mm_reg_f32a(const float* aR0, const float* aR1,
                                            const bf16* bRow0, const bf16* bRow1,
                                            bf16* As, bf16* Bs, int tid,
                                            v4f acc[4][4]) {
  const int wave = tid >> 6, lane = tid & 63;
  const int wr = (wave >> 1) * 64, wc = (wave & 1) * 64;
  const int fr = lane & 15, fq = lane >> 4;
  bf16* a_s0 = As + tid * 8;
  bf16* a_s1 = As + (tid + 256) * 8;
  bf16* b_s0 = Bs + tid * 8;
  bf16* b_s1 = Bs + (tid + 256) * 8;
  const bf16* aF[4];
  const bf16* bF[4];
#pragma unroll
  for (int i = 0; i < 4; ++i) {
    aF[i] = As + (wr + i * 16 + fr) * 32 + fq * 8;
    bF[i] = Bs + (wc + i * 16 + fr) * 32 + fq * 8;
  }
  for (int kk = 0; kk < KTOT; kk += 32) {
    v8bf va0, va1;
    const float* p0 = aR0 + kk;
    const float* p1 = aR1 + kk;
    v4f f00 = ((const v4f*)p0)[0], f01 = ((const v4f*)p0)[1];
    v4f f10 = ((const v4f*)p1)[0], f11 = ((const v4f*)p1)[1];
#pragma unroll
    for (int j = 0; j < 4; ++j) {
      va0[j] = (bf16)f00[j]; va0[j + 4] = (bf16)f01[j];
      va1[j] = (bf16)f10[j]; va1[j + 4] = (bf16)f11[j];
    }
    v8bf vb0 = *(const v8bf*)(bRow0 + kk);
    v8bf vb1 = *(const v8bf*)(bRow1 + kk);
    __syncthreads();
    *(v8bf*)a_s0 = va0;
    *(v8bf*)a_s1 = va1;
    *(v8bf*)b_s0 = vb0;
    *(v8bf*)b_s1 = vb1;
    __syncthreads();
    v8bf av[4], bv[4];
#pragma unroll
    for (int i = 0; i < 4; ++i) av[i] = *(const v8bf*)aF[i];
#pragma unroll
    for (int j = 0; j < 4; ++j) bv[j] = *(const v8bf*)bF[j];
#pragma unroll
    for (int i = 0; i < 4; ++i) {
#pragma unroll
      for (int j = 0; j < 4; ++j) {
        acc[i][j] = __builtin_amdgcn_mfma_f32_16x16x32_bf16(av[i], bv[j], acc[i][j], 0, 0, 0);
      }
    }
  }
  __syncthreads();
}

// ---------------------------------------------------------------- prep
// Merged prep. Long-tail low-parallelism sections FIRST so they overlap the
// big cvt instead of trailing it. All stores vectorized (8-16B packed).
// sections: 8 OHT | 128 gen | 2048 repack | 128 Wf | 128 Whid | nbhb bH16
__global__ void k_prep_all(const float* __restrict__ batch_H, bf16* __restrict__ bH16, int nbhb,
                           const float* __restrict__ W_feat, bf16* __restrict__ Wf16,
                           const float* __restrict__ W_hid, bf16* __restrict__ Whid16,
                           const float* __restrict__ Wih, const float* __restrict__ Whh,
                           bf16* __restrict__ Wcat,
                           const float* __restrict__ Wg, bf16* __restrict__ Wgen16,
                           float* __restrict__ OHT) {
  int b = blockIdx.x;
  const int t = threadIdx.x;
  if (b < 8) {  // OHT transpose: n = b*256+t
    int n = b * 256 + t;
    const float* src = Wih + (size_t)n * 609 + 512;
#pragma unroll 8
    for (int c = 0; c < C_; ++c) OHT[(size_t)c * 2048 + n] = src[c];
    return;
  }
  b -= 8;
  if (b < 128) {  // W_gen rows (pad to 128)
    int row = b;
    int k = t * 2;
    float v0 = (row < C_) ? Wg[(size_t)row * 512 + k] : 0.0f;
    float v1 = (row < C_) ? Wg[(size_t)row * 512 + k + 1] : 0.0f;
    union { bf16 h[2]; uint u; } pk;
    pk.h[0] = (bf16)v0; pk.h[1] = (bf16)v1;
    *(uint*)(Wgen16 + (size_t)row * 512 + k) = pk.u;
    return;
  }
  b -= 128;
  if (b < 2048) {  // Wcat repack: row n = b
    int n = b;
    int k = t * 4;
    float v0, v1, v2, v3;
    if (k < 512) {
      const float* s = Wih + (size_t)n * 609 + k;
      v0 = s[0]; v1 = s[1]; v2 = s[2]; v3 = s[3];
    } else {
      const float* s = Whh + (size_t)n * 512 + (k - 512);
      v0 = s[0]; v1 = s[1]; v2 = s[2]; v3 = s[3];
    }
    store_bf16x4(Wcat + (size_t)n * 1024 + k, v0, v1, v2, v3);
    return;
  }
  b -= 2048;
  if (b < 128) {  // W_feat cvt: 8 elems/thread
    int i = (b * 256 + t) * 8;
    v4f f0 = ((const v4f*)(W_feat + i))[0];
    v4f f1 = ((const v4f*)(W_feat + i))[1];
    store_bf16x8(Wf16 + i, f0, f1);
    return;
  }
  b -= 128;
  if (b < 128) {  // W_hid cvt
    int i = (b * 256 + t) * 8;
    v4f f0 = ((const v4f*)(W_hid + i))[0];
    v4f f1 = ((const v4f*)(W_hid + i))[1];
    store_bf16x8(Whid16 + i, f0, f1);
    return;
  }
  b -= 128;
  if (b < nbhb) {  // batch_H cvt: 8 elems/thread
    int i = (b * 256 + t) * 8;
    v4f f0 = ((const v4f*)(batch_H + i))[0];
    v4f f1 = ((const v4f*)(batch_H + i))[1];
    store_bf16x8(bH16 + i, f0, f1);
  }
}

// ---------------------------------------------------------------- kernels

// F = batch_H . W_feat^T, bf16 input path (quad-buffer depth-2, 2 blocks/CU)
__global__ __launch_bounds__(256, 2) void k_feat16(const bf16* __restrict__ A,
                                                   const bf16* __restrict__ Bw,
                                                   bf16* __restrict__ F) {
  __shared__ bf16 As[4 * 4096];
  __shared__ bf16 Bs[4 * 4096];
  const int tid = threadIdx.x;
  const int m0 = blockIdx.x * 128, n0 = blockIdx.y * 128;
  const int r0 = tid >> 2, k0 = (tid & 3) * 8;
  const bf16* aRow0 = A + (size_t)(m0 + r0) * 512 + k0;
  const bf16* aRow1 = A + (size_t)(m0 + r0 + 64) * 512 + k0;
  const bf16* bRow0 = Bw + (size_t)(n0 + r0) * 512 + k0;
  const bf16* bRow1 = Bw + (size_t)(n0 + r0 + 64) * 512 + k0;
  v4f acc[4][4];
  zero_acc(acc);
  mm_qb32<512>(aRow0, aRow1, bRow0, bRow1, As, Bs, tid, acc);
  const int wave = tid >> 6, lane = tid & 63;
  const int wr = (wave >> 1) * 64, wc = (wave & 1) * 64;
  const int fr = lane & 15, fq = lane >> 4;
#pragma unroll
  for (int i = 0; i < 4; ++i) {
#pragma unroll
    for (int j = 0; j < 4; ++j) {
      int col = n0 + wc + j * 16 + fr;
#pragma unroll
      for (int r = 0; r < 4; ++r) {
        int row = m0 + wr + i * 16 + fq * 4 + r;
        F[(size_t)row * 512 + col] = (bf16)acc[i][j][r];
      }
    }
  }
}

// F = batch_H . W_feat^T, fp32 input fallback (register staging)
__global__ __launch_bounds__(256, 2) void k_feat32(const float* __restrict__ A,
                                                   const bf16* __restrict__ Bw,
                                                   bf16* __restrict__ F) {
  __shared__ bf16 As[128 * 32];
  __shared__ bf16 Bs[128 * 32];
  const int tid = threadIdx.x;
  const int m0 = blockIdx.x * 128, n0 = blockIdx.y * 128;
  const int r0 = tid >> 2, k0 = (tid & 3) * 8;
  const float* aRow0 = A + (size_t)(m0 + r0) * 512 + k0;
  const float* aRow1 = A + (size_t)(m0 + r0 + 64) * 512 + k0;
  const bf16* bRow0 = Bw + (size_t)(n0 + r0) * 512 + k0;
  const bf16* bRow1 = Bw + (size_t)(n0 + r0 + 64) * 512 + k0;
  v4f acc[4][4];
  zero_acc(acc);
  mm_reg_f32a<512>(aRow0, aRow1, bRow0, bRow1, As, Bs, tid, acc);
  const int wave = tid >> 6, lane = tid & 63;
  const int wr = (wave >> 1) * 64, wc = (wave & 1) * 64;
  const int fr = lane & 15, fq = lane >> 4;
#pragma unroll
  for (int i = 0; i < 4; ++i) {
#pragma unroll
    for (int j = 0; j < 4; ++j) {
      int col = n0 + wc + j * 16 + fr;
#pragma unroll
      for (int r = 0; r < 4; ++r) {
        int row = m0 + wr + i * 16 + fq * 4 + r;
        F[(size_t)row * 512 + col] = (bf16)acc[i][j][r];
      }
    }
  }
}

// P = h . W_hid^T + b_hid.  32x64 tiles, flat grid 128 blocks, XCD remap.
__global__ __launch_bounds__(256) void k_hp(const bf16* __restrict__ xb_cur,
                                            const bf16* __restrict__ Whid16,
                                            const float* __restrict__ b_hid,
                                            float* __restrict__ P) {
  __shared__ bf16 As[4 * 2048];
  __shared__ bf16 Bs[4 * 4096];
  const int tid = threadIdx.x, wave = tid >> 6, lane = tid & 63;
  const int flat = blockIdx.x;
  const int m0 = (flat >> 3) * 32;
  const int n0 = (flat & 7) * 64;
  const int fr = lane & 15, fq = lane >> 4;
  const int ra = tid >> 3, sa = (tid & 7) ^ (ra & 7);
  const bf16* aSrc = xb_cur + (size_t)(m0 + ra) * 1024 + 512 + sa * 8;
  const int rb0 = tid >> 3, rb1 = (tid >> 3) + 32;
  const bf16* bSrc0 = Whid16 + (size_t)(n0 + rb0) * 512 + (((tid & 7) ^ (rb0 & 7)) * 8);
  const bf16* bSrc1 = Whid16 + (size_t)(n0 + rb1) * 512 + (((tid & 7) ^ (rb1 & 7)) * 8);
  const int s0 = tid * 8;
  v4f acc[2];
  v4f z = {0.f, 0.f, 0.f, 0.f};
  acc[0] = z; acc[1] = z;
#define STGH(bi, kk)                                    \
  do {                                                  \
    async_copy16(As + (bi) * 2048 + s0, aSrc + (kk));   \
    async_copy16(Bs + (bi) * 4096 + s0, bSrc0 + (kk));  \
    async_copy16(Bs + (bi) * 4096 + 2048 + s0, bSrc1 + (kk)); \
  } while (0)
  STGH(0, 0);
  STGH(1, 64);
  constexpr int NT = 8;
  for (int t = 0; t < NT; ++t) {
    if (t + 2 < NT) {
      STGH((t + 2) & 3, (t + 2) * 64);
      WAITBAR(6);
    } else if (t + 1 < NT) {
      WAITBAR(3);
    } else {
      WAITBAR(0);
    }
    const int cb4 = (t & 3) * 2048;
    const int cb8 = (t & 3) * 4096;
#pragma unroll
    for (int ks = 0; ks < 2; ++ks) {
      const int sw = ((ks * 4 + fq) ^ (fr & 7)) * 8;
      v8bf bv = *(const v8bf*)(Bs + cb8 + (wave * 16 + fr) * 64 + sw);
      __builtin_amdgcn_s_setprio(1);
#pragma unroll
      for (int i = 0; i < 2; ++i) {
        v8bf av = *(const v8bf*)(As + cb4 + (i * 16 + fr) * 64 + sw);
        acc[i] = __builtin_amdgcn_mfma_f32_16x16x32_bf16(av, bv, acc[i], 0, 0, 0);
      }
      __builtin_amdgcn_s_setprio(0);
    }
  }
#undef STGH
  const int col = n0 + wave * 16 + fr;
  const float bh = b_hid[col];
#pragma unroll
  for (int i = 0; i < 2; ++i) {
#pragma unroll
    for (int r = 0; r < 4; ++r) {
      int row = m0 + i * 16 + fq * 4 + r;
      P[(size_t)row * 512 + col] = acc[i][r] + bh;
    }
  }
}

// attn kernel A: e[b][t] = sW - 2*sum_h w_h/(1+exp(2(F+P))).
// grid 2048 = b x 4 t-chunks of 32 rows; 256 thr; high occupancy (6 blk/CU).
__global__ __launch_bounds__(256, 6) void k_attn_e(const bf16* __restrict__ F,
                                                   const float* __restrict__ P,
                                                   const float* __restrict__ w_score,
                                                   float* __restrict__ e_g) {
  const int bid = blockIdx.x;
  const int b = bid >> 2, c = bid & 3;
  const int tid = threadIdx.x, wave = tid >> 6, lane = tid & 63;  // wave 0..3
  const float CF = 2.8853900817779268f;  // 2*log2(e)
  float pl[8], Wv[8];
  {
    const float* p = P + (size_t)b * H_ + lane * 8;
#pragma unroll
    for (int j = 0; j < 8; ++j) pl[j] = CF * p[j];
    const float* w = w_score + lane * 8;
#pragma unroll
    for (int j = 0; j < 8; ++j) Wv[j] = w[j];
  }
  float sW = 0.f;
#pragma unroll
  for (int j = 0; j < 8; ++j) sW += Wv[j];
#pragma unroll
  for (int off = 32; off; off >>= 1) sW += __shfl_xor(sW, off, 64);
  const bf16* Fb = F + (size_t)b * T_ * H_ + lane * 8;
  const int t0 = c * 32 + wave * 8;
#pragma unroll
  for (int kb = 0; kb < 2; ++kb) {
    v8bf r[4];
#pragma unroll
    for (int u = 0; u < 4; ++u)
      r[u] = *(const v8bf*)(Fb + (size_t)(t0 + kb * 4 + u) * H_);
    float a[4];
#pragma unroll
    for (int u = 0; u < 4; ++u) {
      float s = 0.f;
#pragma unroll
      for (int j = 0; j < 8; ++j)
        s = fmaf(Wv[j], __builtin_amdgcn_rcpf(1.0f + exp2f(fmaf(CF, (float)r[u][j], pl[j]))), s);
      a[u] = s;
    }
#pragma unroll
    for (int off = 32; off; off >>= 1) {
#pragma unroll
      for (int u = 0; u < 4; ++u) a[u] += __shfl_xor(a[u], off, 64);
    }
    if (lane == 0) {
#pragma unroll
      for (int u = 0; u < 4; ++u)
        e_g[(size_t)b * T_ + t0 + kb * 4 + u] = sW - 2.0f * a[u];
    }
  }
}

// attn kernel B: per-wave redundant softmax (from e_g) + ctx stream.
__global__ __launch_bounds__(512, 4) void k_attn_ctx(const float* __restrict__ e_g,
                                                     const bf16* __restrict__ bH,
                                                     bf16* __restrict__ xb_cur) {
  const int b = blockIdx.x;
  const int tid = threadIdx.x, wave = tid >> 6, lane = tid & 63;  // wave 0..7
  __shared__ float red[8][I_];
  const int i0 = lane * 8;
  const bf16* hb = bH + (size_t)b * T_ * I_ + i0;
  // issue first batch of loads BEFORE softmax math (independent)
  v8bf p[8];
#pragma unroll
  for (int u = 0; u < 8; ++u)
    p[u] = *(const v8bf*)(hb + (size_t)(wave + u * 8) * I_);
  float x0, x1;
  {
    float e0 = e_g[(size_t)b * T_ + lane];
    float e1 = e_g[(size_t)b * T_ + 64 + lane];
    float m = fmaxf(e0, e1);
#pragma unroll
    for (int off = 32; off; off >>= 1) m = fmaxf(m, __shfl_xor(m, off, 64));
    x0 = __expf(e0 - m);
    x1 = __expf(e1 - m);
    float ssum = x0 + x1;
#pragma unroll
    for (int off = 32; off; off >>= 1) ssum += __shfl_xor(ssum, off, 64);
    float inv = __builtin_amdgcn_rcpf(ssum);
    x0 *= inv;
    x1 *= inv;
  }
  float c[8];
#pragma unroll
  for (int j = 0; j < 8; ++j) c[j] = 0.f;
  float aa[8];
#pragma unroll
  for (int u = 0; u < 8; ++u) aa[u] = __shfl(x0, wave + u * 8, 64);
  v8bf p2[8];
#pragma unroll
  for (int u = 0; u < 8; ++u)
    p2[u] = *(const v8bf*)(hb + (size_t)(64 + wave + u * 8) * I_);
#pragma unroll
  for (int u = 0; u < 8; ++u) {
#pragma unroll
    for (int j = 0; j < 8; ++j) c[j] = fmaf(aa[u], (float)p[u][j], c[j]);
  }
#pragma unroll
  for (int u = 0; u < 8; ++u) aa[u] = __shfl(x1, wave + u * 8, 64);
#pragma unroll
  for (int u = 0; u < 8; ++u) {
#pragma unroll
    for (int j = 0; j < 8; ++j) c[j] = fmaf(aa[u], (float)p2[u][j], c[j]);
  }
#pragma unroll
  for (int j = 0; j < 8; ++j) red[wave][i0 + j] = c[j];
  __syncthreads();
  {
    int i = tid;
    float s = red[0][i] + red[1][i] + red[2][i] + red[3][i] +
              red[4][i] + red[5][i] + red[6][i] + red[7][i];
    xb_cur[(size_t)b * 1024 + i] = (bf16)s;
  }
}

// fallback fused attn (fp32 batch_H path), as in R6
__global__ __launch_bounds__(512, 4) void k_attn_f32(const bf16* __restrict__ F,
                                                     const float* __restrict__ P,
                                                     const float* __restrict__ w_score,
                                                     const float* __restrict__ bHv,
                                                     bf16* __restrict__ xb_cur) {
  const int b = blockIdx.x;
  const int tid = threadIdx.x, wave = tid >> 6, lane = tid & 63;
  __shared__ float e_s[T_];
  __shared__ float red[8][I_];
  const float CF = 2.8853900817779268f;
  float pl[8], Wv[8];
  {
    const float* p = P + (size_t)b * H_ + lane * 8;
#pragma unroll
    for (int j = 0; j < 8; ++j) pl[j] = CF * p[j];
    const float* w = w_score + lane * 8;
#pragma unroll
    for (int j = 0; j < 8; ++j) Wv[j] = w[j];
  }
  float sW = 0.f;
#pragma unroll
  for (int j = 0; j < 8; ++j) sW += Wv[j];
#pragma unroll
  for (int off = 32; off; off >>= 1) sW += __shfl_xor(sW, off, 64);
  const bf16* Fb = F + (size_t)b * T_ * H_ + lane * 8;
#pragma unroll
  for (int kb = 0; kb < 2; ++kb) {
    v8bf r[8];
#pragma unroll
    for (int u = 0; u < 8; ++u)
      r[u] = *(const v8bf*)(Fb + (size_t)(wave + kb * 64 + u * 8) * H_);
    float a[8];
#pragma unroll
    for (int u = 0; u < 8; ++u) {
      float s = 0.f;
#pragma unroll
      for (int j = 0; j < 8; ++j)
        s = fmaf(Wv[j], __builtin_amdgcn_rcpf(1.0f + exp2f(fmaf(CF, (float)r[u][j], pl[j]))), s);
      a[u] = s;
    }
#pragma unroll
    for (int off = 32; off; off >>= 1) {
#pragma unroll
      for (int u = 0; u < 8; ++u) a[u] += __shfl_xor(a[u], off, 64);
    }
    if (lane == 0) {
#pragma unroll
      for (int u = 0; u < 8; ++u) e_s[wave + kb * 64 + u * 8] = sW - 2.0f * a[u];
    }
  }
  __syncthreads();
  float x0, x1;
  {
    float e0 = e_s[lane], e1 = e_s[lane + 64];
    float m = fmaxf(e0, e1);
#pragma unroll
    for (int off = 32; off; off >>= 1) m = fmaxf(m, __shfl_xor(m, off, 64));
    x0 = __expf(e0 - m);
    x1 = __expf(e1 - m);
    float ssum = x0 + x1;
#pragma unroll
    for (int off = 32; off; off >>= 1) ssum += __shfl_xor(ssum, off, 64);
    float inv = __builtin_amdgcn_rcpf(ssum);
    x0 *= inv;
    x1 *= inv;
  }
  const int i0 = lane * 8;
  float c[8];
#pragma unroll
  for (int j = 0; j < 8; ++j) c[j] = 0.f;
  const float* hf = bHv + (size_t)b * T_ * I_ + i0;
#pragma unroll
  for (int k = 0; k < 4; ++k) {
    const int t = wave + 32 * k;
    float xa = (k < 2) ? x0 : x1;
    float aa0 = __shfl(xa, t & 63, 64);
    float aa1 = __shfl(xa, (t + 8) & 63, 64);
    float aa2 = __shfl(xa, (t + 16) & 63, 64);
    float aa3 = __shfl(xa, (t + 24) & 63, 64);
    const float* p0 = hf + (size_t)t * I_;
    const float* p1 = hf + (size_t)(t + 8) * I_;
    const float* p2 = hf + (size_t)(t + 16) * I_;
    const float* p3 = hf + (size_t)(t + 24) * I_;
    v4f q00 = ((const v4f*)p0)[0], q01 = ((const v4f*)p0)[1];
    v4f q10 = ((const v4f*)p1)[0], q11 = ((const v4f*)p1)[1];
    v4f q20 = ((const v4f*)p2)[0], q21 = ((const v4f*)p2)[1];
    v4f q30 = ((const v4f*)p3)[0], q31 = ((const v4f*)p3)[1];
#pragma unroll
    for (int j = 0; j < 4; ++j) {
      c[j]     = fmaf(aa0, q00[j], c[j]);
      c[j + 4] = fmaf(aa0, q01[j], c[j + 4]);
      c[j]     = fmaf(aa1, q10[j], c[j]);
      c[j + 4] = fmaf(aa1, q11[j], c[j + 4]);
      c[j]     = fmaf(aa2, q20[j], c[j]);
      c[j + 4] = fmaf(aa2, q21[j], c[j + 4]);
      c[j]     = fmaf(aa3, q30[j], c[j]);
      c[j + 4] = fmaf(aa3, q31[j], c[j + 4]);
    }
  }
#pragma unroll
  for (int j = 0; j < 8; ++j) red[wave][i0 + j] = c[j];
  __syncthreads();
  {
    int i = tid;
    float s = red[0][i] + red[1][i] + red[2][i] + red[3][i] +
              red[4][i] + red[5][i] + red[6][i] + red[7][i];
    xb_cur[(size_t)b * 1024 + i] = (bf16)s;
  }
}

// gates GEMM + fused one-hot/bias + LSTM (32x128, 256 blocks, XCD remap)
__global__ __launch_bounds__(256) void k_gates(const bf16* __restrict__ xb_cur,
                                               const bf16* __restrict__ Wcat,
                                               const float* __restrict__ OHT,
                                               const float* __restrict__ b_ih,
                                               const float* __restrict__ b_hh,
                                               const int* __restrict__ text,
                                               float* __restrict__ c_state,
                                               bf16* __restrict__ out_h,
                                               bf16* __restrict__ xb_nxt, int s) {
  __shared__ union {
    struct { bf16 A[4 * 2048]; bf16 Bv[4 * 8192]; } st;
    float Cs[32 * 132];
  } sm;
  const int tid = threadIdx.x;
  const int flat = blockIdx.x;
  const int xcd = flat & 7;
  const int idx = flat >> 3;
  const int m0 = (idx >> 1) * 32;
  const int j0 = (xcd * 2 + (idx & 1)) * 32;
  const int wave = tid >> 6, lane = tid & 63;
  const int fr = lane & 15, fq = lane >> 4;
  const int s0 = tid * 8;
  const int ra = tid >> 3, sa = (tid & 7) ^ (ra & 7);
  const bf16* aSrc = xb_cur + (size_t)(m0 + ra) * 1024 + sa * 8;
  const bf16* bSrc[4];
#pragma unroll
  for (int cc = 0; cc < 4; ++cc) {
    const int rb = (tid >> 3) + cc * 32;
    const int nw = (rb >> 5) * 512 + j0 + (rb & 31);
    bSrc[cc] = Wcat + (size_t)nw * 1024 + (((tid & 7) ^ (rb & 7)) * 8);
  }
  v4f acc[2][2];
  {
    v4f z = {0.f, 0.f, 0.f, 0.f};
    acc[0][0] = z; acc[0][1] = z; acc[1][0] = z; acc[1][1] = z;
  }
#define STGG(bi, kk)                                                 \
  do {                                                               \
    async_copy16(sm.st.A + (bi) * 2048 + s0, aSrc + (kk));           \
    async_copy16(sm.st.Bv + (bi) * 8192 + s0, bSrc[0] + (kk));       \
    async_copy16(sm.st.Bv + (bi) * 8192 + 2048 + s0, bSrc[1] + (kk)); \
    async_copy16(sm.st.Bv + (bi) * 8192 + 4096 + s0, bSrc[2] + (kk)); \
    async_copy16(sm.st.Bv + (bi) * 8192 + 6144 + s0, bSrc[3] + (kk)); \
  } while (0)
  STGG(0, 0);
  STGG(1, 64);
  constexpr int NT = 16;
  for (int t = 0; t < NT; ++t) {
    if (t + 2 < NT) {
      STGG((t + 2) & 3, (t + 2) * 64);
      WAITBAR(10);
    } else if (t + 1 < NT) {
      WAITBAR(5);
    } else {
      WAITBAR(0);
    }
    const int ca = (t & 3) * 2048;
    const int cbv = (t & 3) * 8192;
#pragma unroll
    for (int ks = 0; ks < 2; ++ks) {
      const int sw = ((ks * 4 + fq) ^ (fr & 7)) * 8;
      v8bf av[2], bv[2];
#pragma unroll
      for (int i = 0; i < 2; ++i)
        av[i] = *(const v8bf*)(sm.st.A + ca + (i * 16 + fr) * 64 + sw);
#pragma unroll
      for (int jf = 0; jf < 2; ++jf)
        bv[jf] = *(const v8bf*)(sm.st.Bv + cbv + (wave * 32 + jf * 16 + fr) * 64 + sw);
      __builtin_amdgcn_s_setprio(1);
#pragma unroll
      for (int i = 0; i < 2; ++i)
#pragma unroll
        for (int jf = 0; jf < 2; ++jf)
          acc[i][jf] = __builtin_amdgcn_mfma_f32_16x16x32_bf16(av[i], bv[jf], acc[i][jf], 0, 0, 0);
      __builtin_amdgcn_s_setprio(0);
    }
  }
#undef STGG
  __syncthreads();
  int tcv[2][4];
#pragma unroll
  for (int i = 0; i < 2; ++i)
#pragma unroll
    for (int r = 0; r < 4; ++r)
      tcv[i][r] = text[(size_t)(m0 + i * 16 + fq * 4 + r) * S_ + s];
#pragma unroll
  for (int jf = 0; jf < 2; ++jf) {
    int cl = wave * 32 + jf * 16 + fr;
    int nw = (cl >> 5) * 512 + j0 + (cl & 31);
    float bias = b_ih[nw] + b_hh[nw];
    const float* oh = OHT + nw;
#pragma unroll
    for (int i = 0; i < 2; ++i) {
#pragma unroll
      for (int r = 0; r < 4; ++r) {
        int rl = i * 16 + fq * 4 + r;
        sm.Cs[rl * 132 + cl] = acc[i][jf][r] + bias + oh[(size_t)tcv[i][r] * 2048];
      }
    }
  }
  __syncthreads();
#pragma unroll
  for (int it = 0; it < 4; ++it) {
    int idx2 = tid + it * 256;
    int r = idx2 >> 5, q = idx2 & 31;
    float ig = sm.Cs[r * 132 + q];
    float fg = sm.Cs[r * 132 + 32 + q];
    float gg = sm.Cs[r * 132 + 64 + q];
    float og = sm.Cs[r * 132 + 96 + q];
    size_t cix = (size_t)(m0 + r) * 512 + j0 + q;
    float c2 = fast_sigmoid(fg) * c_state[cix] + fast_sigmoid(ig) * fast_tanh(gg);
    float h2 = fast_sigmoid(og) * fast_tanh(c2);
    c_state[cix] = c2;
    bf16 hb = (bf16)h2;
    xb_nxt[(size_t)(m0 + r) * 1024 + 512 + j0 + q] = hb;
    out_h[((size_t)(m0 + r) * S_ + s) * 512 + j0 + q] = hb;
  }
}

// probs = out_h . W_gen^T + b_gen
__global__ __launch_bounds__(256) void k_gen(const bf16* __restrict__ out_h,
                                             const bf16* __restrict__ Wgen16,
                                             const float* __restrict__ b_gen,
                                             float* __restrict__ out) {
  __shared__ bf16 As[4 * 4096];
  __shared__ bf16 Bs[4 * 4096];
  const int tid = threadIdx.x;
  const int m0 = blockIdx.x * 128;
  const int r0 = tid >> 2, k0 = (tid & 3) * 8;
  const bf16* aRow0 = out_h + (size_t)(m0 + r0) * 512 + k0;
  const bf16* aRow1 = out_h + (size_t)(m0 + r0 + 64) * 512 + k0;
  const bf16* bRow0 = Wgen16 + (size_t)r0 * 512 + k0;
  const bf16* bRow1 = Wgen16 + (size_t)(r0 + 64) * 512 + k0;
  v4f acc[4][4];
  zero_acc(acc);
  mm_qb32<512>(aRow0, aRow1, bRow0, bRow1, As, Bs, tid, acc);
  const int wave = tid >> 6, lane = tid & 63;
  const int wr = (wave >> 1) * 64, wc = (wave & 1) * 64;
  const int fr = lane & 15, fq = lane >> 4;
#pragma unroll
  for (int i = 0; i < 4; ++i) {
#pragma unroll
    for (int j = 0; j < 4; ++j) {
      int col = wc + j * 16 + fr;
      if (col < C_) {
        float bg = b_gen[col];
#pragma unroll
        for (int r = 0; r < 4; ++r) {
          int row = m0 + wr + i * 16 + fq * 4 + r;
          out[(size_t)row * C_ + col] = acc[i][j][r] + bg;
        }
      }
    }
  }
}

// ---------------------------------------------------------------- launch
extern "C" void kernel_launch(void* const* d_in, const int* in_sizes, int n_in,
                              void* d_out, int out_size, void* d_ws, size_t ws_size,
                              hipStream_t stream) {
  (void)in_sizes; (void)n_in; (void)out_size;
  const float* batch_H = (const float*)d_in[0];
  const int*   text    = (const int*)d_in[1];
  const float* W_feat  = (const float*)d_in[2];
  const float* W_hid   = (const float*)d_in[3];
  const float* b_hid   = (const float*)d_in[4];
  const float* w_score = (const float*)d_in[5];
  const float* W_ih    = (const float*)d_in[6];
  const float* W_hh    = (const float*)d_in[7];
  const float* b_ih    = (const float*)d_in[8];
  const float* b_hh    = (const float*)d_in[9];
  const float* W_gen   = (const float*)d_in[10];
  const float* b_gen   = (const float*)d_in[11];
  float* out = (float*)d_out;

  char* ws = (char*)d_ws;
  bf16*  F       = (bf16*)(ws);                  // 67108864
  bf16*  out_h   = (bf16*)(ws + 67108864);       // 13631488
  float* P       = (float*)(ws + 80740352);      // 1048576
  bf16*  xb0     = (bf16*)(ws + 81788928);       // 1048576
  bf16*  xb1     = (bf16*)(ws + 82837504);       // 1048576
  float* c_state = (float*)(ws + 83886080);      // 1048576
  bf16*  Wcat    = (bf16*)(ws + 84934656);       // 4194304
  bf16*  Wf16    = (bf16*)(ws + 89128960);       // 524288
  bf16*  Whid16  = (bf16*)(ws + 89653248);       // 524288
  bf16*  Wgen16  = (bf16*)(ws + 90177536);       // 131072
  float* OHT     = (float*)(ws + 90308608);      // 794624 (pad to 1048576)
  bf16*  bH16    = (bf16*)(ws + 91357184);       // 67108864 -> total 158466048
  const bool useBH16 = (ws_size >= (size_t)158466048);

  bf16* xb[2] = {xb0, xb1};

  hipMemsetAsync(xb0, 0, (size_t)512 * 1024 * 2, stream);
  hipMemsetAsync(c_state, 0, (size_t)512 * 512 * 4, stream);

  const int nbhb = useBH16 ? 16384 : 0;  // bH16 cvt blocks (8 elems/thread)
  k_prep_all<<<dim3(2440 + nbhb), 256, 0, stream>>>(
      batch_H, bH16, nbhb, W_feat, Wf16, W_hid, Whid16,
      W_ih, W_hh, Wcat, W_gen, Wgen16, OHT);

  if (useBH16) {
    k_feat16<<<dim3(512, 4), 256, 0, stream>>>(bH16, Wf16, F);
  } else {
    k_feat32<<<dim3(512, 4), 256, 0, stream>>>(batch_H, Wf16, F);
  }

  for (int s = 0; s < S_; ++s) {
    bf16* cur = xb[s & 1];
    bf16* nxt = xb[(s + 1) & 1];
    k_hp<<<dim3(128), 256, 0, stream>>>(cur, Whid16, b_hid, P);
    if (useBH16) {
      // e buffer lives in nxt's first 256KB: those bytes are fully rewritten
      // by k_gates (h-half) after k_attn_ctx consumes e; cross-step safe.
      float* e_g = (float*)nxt;
      k_attn_e<<<dim3(2048), 256, 0, stream>>>(F, P, w_score, e_g);
      k_attn_ctx<<<dim3(512), 512, 0, stream>>>(e_g, bH16, cur);
    } else {
      k_attn_f32<<<dim3(512), 512, 0, stream>>>(F, P, w_score, batch_H, cur);
    }
    k_gates<<<dim3(256), 256, 0, stream>>>(cur, Wcat, OHT, b_ih, b_hh, text,
                                           c_state, out_h, nxt, s);
  }
  k_gen<<<dim3(104, 1), 256, 0, stream>>>(out_h, Wgen16, b_gen, out);
}

// Round 9
// 1423.562 us; speedup vs baseline: 1.0381x; 1.0381x over previous
//
#include <hip/hip_runtime.h>
#include <hip/hip_bf16.h>
#include <stdint.h>
#include <stddef.h>

typedef __bf16 bf16;
typedef __bf16 v8bf __attribute__((ext_vector_type(8)));
typedef float  v4f  __attribute__((ext_vector_type(4)));

#define B_ 512
#define T_ 128
#define I_ 512
#define H_ 512
#define C_ 97
#define S_ 26

// ---------------------------------------------------------------- helpers
__device__ __forceinline__ void async_copy16(void* lds, const void* g) {
  __builtin_amdgcn_global_load_lds((__attribute__((address_space(1))) void*)g,
                                   (__attribute__((address_space(3))) void*)lds,
                                   16, 0, 0);
}

__device__ __forceinline__ float fast_tanh(float x) {
  float e = __expf(2.0f * x);
  return fmaf(-2.0f, __builtin_amdgcn_rcpf(e + 1.0f), 1.0f);
}
__device__ __forceinline__ float fast_sigmoid(float x) {
  float t = __expf(-x);
  return __builtin_amdgcn_rcpf(1.0f + t);
}

__device__ __forceinline__ void zero_acc(v4f acc[4][4]) {
  v4f z = {0.f, 0.f, 0.f, 0.f};
#pragma unroll
  for (int i = 0; i < 4; ++i)
#pragma unroll
    for (int j = 0; j < 4; ++j) acc[i][j] = z;
}

// packed bf16 stores (hipcc won't vectorize scalar bf16 stores)
__device__ __forceinline__ void store_bf16x8(bf16* dst, v4f a, v4f b) {
  union { bf16 h[8]; uint4 u; } pk;
#pragma unroll
  for (int j = 0; j < 4; ++j) { pk.h[j] = (bf16)a[j]; pk.h[4 + j] = (bf16)b[j]; }
  *(uint4*)dst = pk.u;
}
__device__ __forceinline__ void store_bf16x4(bf16* dst, float a0, float a1,
                                             float a2, float a3) {
  union { bf16 h[4]; uint2 u; } pk;
  pk.h[0] = (bf16)a0; pk.h[1] = (bf16)a1; pk.h[2] = (bf16)a2; pk.h[3] = (bf16)a3;
  *(uint2*)dst = pk.u;
}

// T3/T4 sync primitive: counted vmcnt (never 0 mid-loop) + raw barrier.
#define WAITBAR(N)                                             \
  do {                                                         \
    asm volatile("s_waitcnt vmcnt(" #N ")" ::: "memory");      \
    __builtin_amdgcn_s_barrier();                              \
    __builtin_amdgcn_sched_barrier(0);                         \
  } while (0)

// ---------------- 128x128 tile, BK=32, quad-buffer depth-2 prefetch
template <int KTOT>
__device__ __forceinline__ void mm_qb32(const bf16* aRow0, const bf16* aRow1,
                                        const bf16* bRow0, const bf16* bRow1,
                                        bf16* As, bf16* Bs, int tid,
                                        v4f acc[4][4]) {
  constexpr int NT = KTOT / 32;  // >= 3
  const int wave = tid >> 6, lane = tid & 63;
  const int wr = (wave >> 1) * 64, wc = (wave & 1) * 64;
  const int fr = lane & 15, fq = lane >> 4;
  const int s0 = tid * 8;
  const int aB = (wr + fr) * 32 + fq * 8;
  const int bB = (wc + fr) * 32 + fq * 8;
#define STG32(bi, kk)                                   \
  do {                                                  \
    const int o = (bi) * 4096 + s0;                     \
    async_copy16(As + o, aRow0 + (kk));                 \
    async_copy16(As + o + 2048, aRow1 + (kk));          \
    async_copy16(Bs + o, bRow0 + (kk));                 \
    async_copy16(Bs + o + 2048, bRow1 + (kk));          \
  } while (0)
  STG32(0, 0);
  STG32(1, 32);
  for (int t = 0; t < NT; ++t) {
    if (t + 2 < NT) {
      STG32((t + 2) & 3, (t + 2) * 32);
      WAITBAR(8);
    } else if (t + 1 < NT) {
      WAITBAR(4);
    } else {
      WAITBAR(0);
    }
    const int cb = (t & 3) * 4096;
    v8bf av[4], bv[4];
#pragma unroll
    for (int i = 0; i < 4; ++i) av[i] = *(const v8bf*)(As + cb + aB + i * 512);
#pragma unroll
    for (int j = 0; j < 4; ++j) bv[j] = *(const v8bf*)(Bs + cb + bB + j * 512);
    __builtin_amdgcn_s_setprio(1);
#pragma unroll
    for (int i = 0; i < 4; ++i) {
#pragma unroll
      for (int j = 0; j < 4; ++j) {
        acc[i][j] = __builtin_amdgcn_mfma_f32_16x16x32_bf16(av[i], bv[j], acc[i][j], 0, 0, 0);
      }
    }
    __builtin_amdgcn_s_setprio(0);
  }
#undef STG32
}

// ---------------------- fallback 128x128 mainloop (fp32 A, register staging)
template <int KTOT>
__device__ __forceinline__ void mm_reg_f32a(const float* aR0, const float* aR1,
                                            const bf16* bRow0, const bf16* bRow1,
                                            bf16* As, bf16* Bs, int tid,
                                            v4f acc[4][4]) {
  const int wave = tid >> 6, lane = tid & 63;
  const int wr = (wave >> 1) * 64, wc = (wave & 1) * 64;
  const int fr = lane & 15, fq = lane >> 4;
  bf16* a_s0 = As + tid * 8;
  bf16* a_s1 = As + (tid + 256) * 8;
  bf16* b_s0 = Bs + tid * 8;
  bf16* b_s1 = Bs + (tid + 256) * 8;
  const bf16* aF[4];
  const bf16* bF[4];
#pragma unroll
  for (int i = 0; i < 4; ++i) {
    aF[i] = As + (wr + i * 16 + fr) * 32 + fq * 8;
    bF[i] = Bs + (wc + i * 16 + fr) * 32 + fq * 8;
  }
  for (int kk = 0; kk < KTOT; kk += 32) {
    v8bf va0, va1;
    const float* p0 = aR0 + kk;
    const float* p1 = aR1 + kk;
    v4f f00 = ((const v4f*)p0)[0], f01 = ((const v4f*)p0)[1];
    v4f f10 = ((const v4f*)p1)[0], f11 = ((const v4f*)p1)[1];
#pragma unroll
    for (int j = 0; j < 4; ++j) {
      va0[j] = (bf16)f00[j]; va0[j + 4] = (bf16)f01[j];
      va1[j] = (bf16)f10[j]; va1[j + 4] = (bf16)f11[j];
    }
    v8bf vb0 = *(const v8bf*)(bRow0 + kk);
    v8bf vb1 = *(const v8bf*)(bRow1 + kk);
    __syncthreads();
    *(v8bf*)a_s0 = va0;
    *(v8bf*)a_s1 = va1;
    *(v8bf*)b_s0 = vb0;
    *(v8bf*)b_s1 = vb1;
    __syncthreads();
    v8bf av[4], bv[4];
#pragma unroll
    for (int i = 0; i < 4; ++i) av[i] = *(const v8bf*)aF[i];
#pragma unroll
    for (int j = 0; j < 4; ++j) bv[j] = *(const v8bf*)bF[j];
#pragma unroll
    for (int i = 0; i < 4; ++i) {
#pragma unroll
      for (int j = 0; j < 4; ++j) {
        acc[i][j] = __builtin_amdgcn_mfma_f32_16x16x32_bf16(av[i], bv[j], acc[i][j], 0, 0, 0);
      }
    }
  }
  __syncthreads();
}

// ---------------------------------------------------------------- prep
// Merged prep. Long-tail low-parallelism sections FIRST so they overlap the
// big cvt instead of trailing it. All stores vectorized (8-16B packed).
// sections: 8 OHT | 128 gen | 2048 repack | 128 Wf | 128 Whid | nbhb bH16
__global__ void k_prep_all(const float* __restrict__ batch_H, bf16* __restrict__ bH16, int nbhb,
                           const float* __restrict__ W_feat, bf16* __restrict__ Wf16,
                           const float* __restrict__ W_hid, bf16* __restrict__ Whid16,
                           const float* __restrict__ Wih, const float* __restrict__ Whh,
                           bf16* __restrict__ Wcat,
                           const float* __restrict__ Wg, bf16* __restrict__ Wgen16,
                           float* __restrict__ OHT) {
  int b = blockIdx.x;
  const int t = threadIdx.x;
  if (b < 8) {  // OHT transpose: n = b*256+t
    int n = b * 256 + t;
    const float* src = Wih + (size_t)n * 609 + 512;
#pragma unroll 8
    for (int c = 0; c < C_; ++c) OHT[(size_t)c * 2048 + n] = src[c];
    return;
  }
  b -= 8;
  if (b < 128) {  // W_gen rows (pad to 128)
    int row = b;
    int k = t * 2;
    float v0 = (row < C_) ? Wg[(size_t)row * 512 + k] : 0.0f;
    float v1 = (row < C_) ? Wg[(size_t)row * 512 + k + 1] : 0.0f;
    union { bf16 h[2]; uint u; } pk;
    pk.h[0] = (bf16)v0; pk.h[1] = (bf16)v1;
    *(uint*)(Wgen16 + (size_t)row * 512 + k) = pk.u;
    return;
  }
  b -= 128;
  if (b < 2048) {  // Wcat repack: row n = b
    int n = b;
    int k = t * 4;
    float v0, v1, v2, v3;
    if (k < 512) {
      const float* s = Wih + (size_t)n * 609 + k;
      v0 = s[0]; v1 = s[1]; v2 = s[2]; v3 = s[3];
    } else {
      const float* s = Whh + (size_t)n * 512 + (k - 512);
      v0 = s[0]; v1 = s[1]; v2 = s[2]; v3 = s[3];
    }
    store_bf16x4(Wcat + (size_t)n * 1024 + k, v0, v1, v2, v3);
    return;
  }
  b -= 2048;
  if (b < 128) {  // W_feat cvt: 8 elems/thread
    int i = (b * 256 + t) * 8;
    v4f f0 = ((const v4f*)(W_feat + i))[0];
    v4f f1 = ((const v4f*)(W_feat + i))[1];
    store_bf16x8(Wf16 + i, f0, f1);
    return;
  }
  b -= 128;
  if (b < 128) {  // W_hid cvt
    int i = (b * 256 + t) * 8;
    v4f f0 = ((const v4f*)(W_hid + i))[0];
    v4f f1 = ((const v4f*)(W_hid + i))[1];
    store_bf16x8(Whid16 + i, f0, f1);
    return;
  }
  b -= 128;
  if (b < nbhb) {  // batch_H cvt: 8 elems/thread
    int i = (b * 256 + t) * 8;
    v4f f0 = ((const v4f*)(batch_H + i))[0];
    v4f f1 = ((const v4f*)(batch_H + i))[1];
    store_bf16x8(bH16 + i, f0, f1);
  }
}

// ---------------------------------------------------------------- kernels

// F = batch_H . W_feat^T, bf16 input path (quad-buffer depth-2, 2 blocks/CU)
__global__ __launch_bounds__(256, 2) void k_feat16(const bf16* __restrict__ A,
                                                   const bf16* __restrict__ Bw,
                                                   bf16* __restrict__ F) {
  __shared__ bf16 As[4 * 4096];
  __shared__ bf16 Bs[4 * 4096];
  const int tid = threadIdx.x;
  const int m0 = blockIdx.x * 128, n0 = blockIdx.y * 128;
  const int r0 = tid >> 2, k0 = (tid & 3) * 8;
  const bf16* aRow0 = A + (size_t)(m0 + r0) * 512 + k0;
  const bf16* aRow1 = A + (size_t)(m0 + r0 + 64) * 512 + k0;
  const bf16* bRow0 = Bw + (size_t)(n0 + r0) * 512 + k0;
  const bf16* bRow1 = Bw + (size_t)(n0 + r0 + 64) * 512 + k0;
  v4f acc[4][4];
  zero_acc(acc);
  mm_qb32<512>(aRow0, aRow1, bRow0, bRow1, As, Bs, tid, acc);
  const int wave = tid >> 6, lane = tid & 63;
  const int wr = (wave >> 1) * 64, wc = (wave & 1) * 64;
  const int fr = lane & 15, fq = lane >> 4;
#pragma unroll
  for (int i = 0; i < 4; ++i) {
#pragma unroll
    for (int j = 0; j < 4; ++j) {
      int col = n0 + wc + j * 16 + fr;
#pragma unroll
      for (int r = 0; r < 4; ++r) {
        int row = m0 + wr + i * 16 + fq * 4 + r;
        F[(size_t)row * 512 + col] = (bf16)acc[i][j][r];
      }
    }
  }
}

// F = batch_H . W_feat^T, fp32 input fallback (register staging)
__global__ __launch_bounds__(256, 2) void k_feat32(const float* __restrict__ A,
                                                   const bf16* __restrict__ Bw,
                                                   bf16* __restrict__ F) {
  __shared__ bf16 As[128 * 32];
  __shared__ bf16 Bs[128 * 32];
  const int tid = threadIdx.x;
  const int m0 = blockIdx.x * 128, n0 = blockIdx.y * 128;
  const int r0 = tid >> 2, k0 = (tid & 3) * 8;
  const float* aRow0 = A + (size_t)(m0 + r0) * 512 + k0;
  const float* aRow1 = A + (size_t)(m0 + r0 + 64) * 512 + k0;
  const bf16* bRow0 = Bw + (size_t)(n0 + r0) * 512 + k0;
  const bf16* bRow1 = Bw + (size_t)(n0 + r0 + 64) * 512 + k0;
  v4f acc[4][4];
  zero_acc(acc);
  mm_reg_f32a<512>(aRow0, aRow1, bRow0, bRow1, As, Bs, tid, acc);
  const int wave = tid >> 6, lane = tid & 63;
  const int wr = (wave >> 1) * 64, wc = (wave & 1) * 64;
  const int fr = lane & 15, fq = lane >> 4;
#pragma unroll
  for (int i = 0; i < 4; ++i) {
#pragma unroll
    for (int j = 0; j < 4; ++j) {
      int col = n0 + wc + j * 16 + fr;
#pragma unroll
      for (int r = 0; r < 4; ++r) {
        int row = m0 + wr + i * 16 + fq * 4 + r;
        F[(size_t)row * 512 + col] = (bf16)acc[i][j][r];
      }
    }
  }
}

// P = h . W_hid^T + b_hid.  32x64 tiles, flat grid 128 blocks, XCD remap.
__global__ __launch_bounds__(256) void k_hp(const bf16* __restrict__ xb_cur,
                                            const bf16* __restrict__ Whid16,
                                            const float* __restrict__ b_hid,
                                            float* __restrict__ P) {
  __shared__ bf16 As[4 * 2048];
  __shared__ bf16 Bs[4 * 4096];
  const int tid = threadIdx.x, wave = tid >> 6, lane = tid & 63;
  const int flat = blockIdx.x;
  const int m0 = (flat >> 3) * 32;
  const int n0 = (flat & 7) * 64;
  const int fr = lane & 15, fq = lane >> 4;
  const int ra = tid >> 3, sa = (tid & 7) ^ (ra & 7);
  const bf16* aSrc = xb_cur + (size_t)(m0 + ra) * 1024 + 512 + sa * 8;
  const int rb0 = tid >> 3, rb1 = (tid >> 3) + 32;
  const bf16* bSrc0 = Whid16 + (size_t)(n0 + rb0) * 512 + (((tid & 7) ^ (rb0 & 7)) * 8);
  const bf16* bSrc1 = Whid16 + (size_t)(n0 + rb1) * 512 + (((tid & 7) ^ (rb1 & 7)) * 8);
  const int s0 = tid * 8;
  v4f acc[2];
  v4f z = {0.f, 0.f, 0.f, 0.f};
  acc[0] = z; acc[1] = z;
#define STGH(bi, kk)                                    \
  do {                                                  \
    async_copy16(As + (bi) * 2048 + s0, aSrc + (kk));   \
    async_copy16(Bs + (bi) * 4096 + s0, bSrc0 + (kk));  \
    async_copy16(Bs + (bi) * 4096 + 2048 + s0, bSrc1 + (kk)); \
  } while (0)
  STGH(0, 0);
  STGH(1, 64);
  constexpr int NT = 8;
  for (int t = 0; t < NT; ++t) {
    if (t + 2 < NT) {
      STGH((t + 2) & 3, (t + 2) * 64);
      WAITBAR(6);
    } else if (t + 1 < NT) {
      WAITBAR(3);
    } else {
      WAITBAR(0);
    }
    const int cb4 = (t & 3) * 2048;
    const int cb8 = (t & 3) * 4096;
#pragma unroll
    for (int ks = 0; ks < 2; ++ks) {
      const int sw = ((ks * 4 + fq) ^ (fr & 7)) * 8;
      v8bf bv = *(const v8bf*)(Bs + cb8 + (wave * 16 + fr) * 64 + sw);
      __builtin_amdgcn_s_setprio(1);
#pragma unroll
      for (int i = 0; i < 2; ++i) {
        v8bf av = *(const v8bf*)(As + cb4 + (i * 16 + fr) * 64 + sw);
        acc[i] = __builtin_amdgcn_mfma_f32_16x16x32_bf16(av, bv, acc[i], 0, 0, 0);
      }
      __builtin_amdgcn_s_setprio(0);
    }
  }
#undef STGH
  const int col = n0 + wave * 16 + fr;
  const float bh = b_hid[col];
#pragma unroll
  for (int i = 0; i < 2; ++i) {
#pragma unroll
    for (int r = 0; r < 4; ++r) {
      int row = m0 + i * 16 + fq * 4 + r;
      P[(size_t)row * 512 + col] = acc[i][r] + bh;
    }
  }
}

// fused attention (R6 structure). 8 waves, 8 rows in flight per wave.
// Sum-w trick: w*tanh(x) = w - 2*w/(1+2^(cf*x')); softmax redundant per wave.
template <bool CTX16>
__global__ __launch_bounds__(512, 4) void k_attn(const bf16* __restrict__ F,
                                                 const float* __restrict__ P,
                                                 const float* __restrict__ w_score,
                                                 const void* __restrict__ bHv,
                                                 bf16* __restrict__ xb_cur) {
  const int b = blockIdx.x;
  const int tid = threadIdx.x, wave = tid >> 6, lane = tid & 63;  // wave 0..7
  __shared__ float e_s[T_];
  __shared__ float red[8][I_];
  const float CF = 2.8853900817779268f;  // 2*log2(e)
  float pl[8], Wv[8];
  {
    const float* p = P + (size_t)b * H_ + lane * 8;
#pragma unroll
    for (int j = 0; j < 8; ++j) pl[j] = CF * p[j];
    const float* w = w_score + lane * 8;
#pragma unroll
    for (int j = 0; j < 8; ++j) Wv[j] = w[j];
  }
  float sW = 0.f;
#pragma unroll
  for (int j = 0; j < 8; ++j) sW += Wv[j];
#pragma unroll
  for (int off = 32; off; off >>= 1) sW += __shfl_xor(sW, off, 64);
  const bf16* Fb = F + (size_t)b * T_ * H_ + lane * 8;
#pragma unroll
  for (int kb = 0; kb < 2; ++kb) {
    v8bf r[8];
#pragma unroll
    for (int u = 0; u < 8; ++u)
      r[u] = *(const v8bf*)(Fb + (size_t)(wave + kb * 64 + u * 8) * H_);
    float a[8];
#pragma unroll
    for (int u = 0; u < 8; ++u) {
      float s = 0.f;
#pragma unroll
      for (int j = 0; j < 8; ++j)
        s = fmaf(Wv[j], __builtin_amdgcn_rcpf(1.0f + exp2f(fmaf(CF, (float)r[u][j], pl[j]))), s);
      a[u] = s;
    }
#pragma unroll
    for (int off = 32; off; off >>= 1) {
#pragma unroll
      for (int u = 0; u < 8; ++u) a[u] += __shfl_xor(a[u], off, 64);
    }
    if (lane == 0) {
#pragma unroll
      for (int u = 0; u < 8; ++u) e_s[wave + kb * 64 + u * 8] = sW - 2.0f * a[u];
    }
  }
  __syncthreads();
  const int i0 = lane * 8;
  float c[8];
#pragma unroll
  for (int j = 0; j < 8; ++j) c[j] = 0.f;
  if (CTX16) {
    const bf16* hb = (const bf16*)bHv + (size_t)b * T_ * I_ + i0;
    // issue first batch of loads BEFORE softmax math (independent)
    v8bf p[8];
#pragma unroll
    for (int u = 0; u < 8; ++u)
      p[u] = *(const v8bf*)(hb + (size_t)(wave + u * 8) * I_);
    float x0, x1;
    {
      float e0 = e_s[lane], e1 = e_s[lane + 64];
      float m = fmaxf(e0, e1);
#pragma unroll
      for (int off = 32; off; off >>= 1) m = fmaxf(m, __shfl_xor(m, off, 64));
      x0 = __expf(e0 - m);
      x1 = __expf(e1 - m);
      float ssum = x0 + x1;
#pragma unroll
      for (int off = 32; off; off >>= 1) ssum += __shfl_xor(ssum, off, 64);
      float inv = __builtin_amdgcn_rcpf(ssum);
      x0 *= inv;
      x1 *= inv;
    }
    float aa[8];
#pragma unroll
    for (int u = 0; u < 8; ++u) aa[u] = __shfl(x0, wave + u * 8, 64);
    v8bf p2[8];
#pragma unroll
    for (int u = 0; u < 8; ++u)
      p2[u] = *(const v8bf*)(hb + (size_t)(64 + wave + u * 8) * I_);
#pragma unroll
    for (int u = 0; u < 8; ++u) {
#pragma unroll
      for (int j = 0; j < 8; ++j) c[j] = fmaf(aa[u], (float)p[u][j], c[j]);
    }
#pragma unroll
    for (int u = 0; u < 8; ++u) aa[u] = __shfl(x1, wave + u * 8, 64);
#pragma unroll
    for (int u = 0; u < 8; ++u) {
#pragma unroll
      for (int j = 0; j < 8; ++j) c[j] = fmaf(aa[u], (float)p2[u][j], c[j]);
    }
  } else {
    float x0, x1;
    {
      float e0 = e_s[lane], e1 = e_s[lane + 64];
      float m = fmaxf(e0, e1);
#pragma unroll
      for (int off = 32; off; off >>= 1) m = fmaxf(m, __shfl_xor(m, off, 64));
      x0 = __expf(e0 - m);
      x1 = __expf(e1 - m);
      float ssum = x0 + x1;
#pragma unroll
      for (int off = 32; off; off >>= 1) ssum += __shfl_xor(ssum, off, 64);
      float inv = __builtin_amdgcn_rcpf(ssum);
      x0 *= inv;
      x1 *= inv;
    }
    const float* hf = (const float*)bHv + (size_t)b * T_ * I_ + i0;
#pragma unroll
    for (int k = 0; k < 4; ++k) {
      const int t = wave + 32 * k;
      float xa = (k < 2) ? x0 : x1;
      float aa0 = __shfl(xa, t & 63, 64);
      float aa1 = __shfl(xa, (t + 8) & 63, 64);
      float aa2 = __shfl(xa, (t + 16) & 63, 64);
      float aa3 = __shfl(xa, (t + 24) & 63, 64);
      const float* p0 = hf + (size_t)t * I_;
      const float* p1 = hf + (size_t)(t + 8) * I_;
      const float* p2 = hf + (size_t)(t + 16) * I_;
      const float* p3 = hf + (size_t)(t + 24) * I_;
      v4f q00 = ((const v4f*)p0)[0], q01 = ((const v4f*)p0)[1];
      v4f q10 = ((const v4f*)p1)[0], q11 = ((const v4f*)p1)[1];
      v4f q20 = ((const v4f*)p2)[0], q21 = ((const v4f*)p2)[1];
      v4f q30 = ((const v4f*)p3)[0], q31 = ((const v4f*)p3)[1];
#pragma unroll
      for (int j = 0; j < 4; ++j) {
        c[j]     = fmaf(aa0, q00[j], c[j]);
        c[j + 4] = fmaf(aa0, q01[j], c[j + 4]);
        c[j]     = fmaf(aa1, q10[j], c[j]);
        c[j + 4] = fmaf(aa1, q11[j], c[j + 4]);
        c[j]     = fmaf(aa2, q20[j], c[j]);
        c[j + 4] = fmaf(aa2, q21[j], c[j + 4]);
        c[j]     = fmaf(aa3, q30[j], c[j]);
        c[j + 4] = fmaf(aa3, q31[j], c[j + 4]);
      }
    }
  }
#pragma unroll
  for (int j = 0; j < 8; ++j) red[wave][i0 + j] = c[j];
  __syncthreads();
  {
    int i = tid;  // 512 threads, 512 outputs
    float s = red[0][i] + red[1][i] + red[2][i] + red[3][i] +
              red[4][i] + red[5][i] + red[6][i] + red[7][i];
    xb_cur[(size_t)b * 1024 + i] = (bf16)s;
  }
}

// gates GEMM + fused one-hot/bias + LSTM (32x128, 256 blocks, XCD remap)
__global__ __launch_bounds__(256) void k_gates(const bf16* __restrict__ xb_cur,
                                               const bf16* __restrict__ Wcat,
                                               const float* __restrict__ OHT,
                                               const float* __restrict__ b_ih,
                                               const float* __restrict__ b_hh,
                                               const int* __restrict__ text,
                                               float* __restrict__ c_state,
                                               bf16* __restrict__ out_h,
                                               bf16* __restrict__ xb_nxt, int s) {
  __shared__ union {
    struct { bf16 A[4 * 2048]; bf16 Bv[4 * 8192]; } st;
    float Cs[32 * 132];
  } sm;
  const int tid = threadIdx.x;
  const int flat = blockIdx.x;
  const int xcd = flat & 7;
  const int idx = flat >> 3;
  const int m0 = (idx >> 1) * 32;
  const int j0 = (xcd * 2 + (idx & 1)) * 32;
  const int wave = tid >> 6, lane = tid & 63;
  const int fr = lane & 15, fq = lane >> 4;
  const int s0 = tid * 8;
  const int ra = tid >> 3, sa = (tid & 7) ^ (ra & 7);
  const bf16* aSrc = xb_cur + (size_t)(m0 + ra) * 1024 + sa * 8;
  const bf16* bSrc[4];
#pragma unroll
  for (int cc = 0; cc < 4; ++cc) {
    const int rb = (tid >> 3) + cc * 32;
    const int nw = (rb >> 5) * 512 + j0 + (rb & 31);
    bSrc[cc] = Wcat + (size_t)nw * 1024 + (((tid & 7) ^ (rb & 7)) * 8);
  }
  v4f acc[2][2];
  {
    v4f z = {0.f, 0.f, 0.f, 0.f};
    acc[0][0] = z; acc[0][1] = z; acc[1][0] = z; acc[1][1] = z;
  }
#define STGG(bi, kk)                                                 \
  do {                                                               \
    async_copy16(sm.st.A + (bi) * 2048 + s0, aSrc + (kk));           \
    async_copy16(sm.st.Bv + (bi) * 8192 + s0, bSrc[0] + (kk));       \
    async_copy16(sm.st.Bv + (bi) * 8192 + 2048 + s0, bSrc[1] + (kk)); \
    async_copy16(sm.st.Bv + (bi) * 8192 + 4096 + s0, bSrc[2] + (kk)); \
    async_copy16(sm.st.Bv + (bi) * 8192 + 6144 + s0, bSrc[3] + (kk)); \
  } while (0)
  STGG(0, 0);
  STGG(1, 64);
  constexpr int NT = 16;
  for (int t = 0; t < NT; ++t) {
    if (t + 2 < NT) {
      STGG((t + 2) & 3, (t + 2) * 64);
      WAITBAR(10);
    } else if (t + 1 < NT) {
      WAITBAR(5);
    } else {
      WAITBAR(0);
    }
    const int ca = (t & 3) * 2048;
    const int cbv = (t & 3) * 8192;
#pragma unroll
    for (int ks = 0; ks < 2; ++ks) {
      const int sw = ((ks * 4 + fq) ^ (fr & 7)) * 8;
      v8bf av[2], bv[2];
#pragma unroll
      for (int i = 0; i < 2; ++i)
        av[i] = *(const v8bf*)(sm.st.A + ca + (i * 16 + fr) * 64 + sw);
#pragma unroll
      for (int jf = 0; jf < 2; ++jf)
        bv[jf] = *(const v8bf*)(sm.st.Bv + cbv + (wave * 32 + jf * 16 + fr) * 64 + sw);
      __builtin_amdgcn_s_setprio(1);
#pragma unroll
      for (int i = 0; i < 2; ++i)
#pragma unroll
        for (int jf = 0; jf < 2; ++jf)
          acc[i][jf] = __builtin_amdgcn_mfma_f32_16x16x32_bf16(av[i], bv[jf], acc[i][jf], 0, 0, 0);
      __builtin_amdgcn_s_setprio(0);
    }
  }
#undef STGG
  __syncthreads();
  int tcv[2][4];
#pragma unroll
  for (int i = 0; i < 2; ++i)
#pragma unroll
    for (int r = 0; r < 4; ++r)
      tcv[i][r] = text[(size_t)(m0 + i * 16 + fq * 4 + r) * S_ + s];
#pragma unroll
  for (int jf = 0; jf < 2; ++jf) {
    int cl = wave * 32 + jf * 16 + fr;
    int nw = (cl >> 5) * 512 + j0 + (cl & 31);
    float bias = b_ih[nw] + b_hh[nw];
    const float* oh = OHT + nw;
#pragma unroll
    for (int i = 0; i < 2; ++i) {
#pragma unroll
      for (int r = 0; r < 4; ++r) {
        int rl = i * 16 + fq * 4 + r;
        sm.Cs[rl * 132 + cl] = acc[i][jf][r] + bias + oh[(size_t)tcv[i][r] * 2048];
      }
    }
  }
  __syncthreads();
#pragma unroll
  for (int it = 0; it < 4; ++it) {
    int idx2 = tid + it * 256;
    int r = idx2 >> 5, q = idx2 & 31;
    float ig = sm.Cs[r * 132 + q];
    float fg = sm.Cs[r * 132 + 32 + q];
    float gg = sm.Cs[r * 132 + 64 + q];
    float og = sm.Cs[r * 132 + 96 + q];
    size_t cix = (size_t)(m0 + r) * 512 + j0 + q;
    float c2 = fast_sigmoid(fg) * c_state[cix] + fast_sigmoid(ig) * fast_tanh(gg);
    float h2 = fast_sigmoid(og) * fast_tanh(c2);
    c_state[cix] = c2;
    bf16 hb = (bf16)h2;
    xb_nxt[(size_t)(m0 + r) * 1024 + 512 + j0 + q] = hb;
    out_h[((size_t)(m0 + r) * S_ + s) * 512 + j0 + q] = hb;
  }
}

// probs = out_h . W_gen^T + b_gen
__global__ __launch_bounds__(256) void k_gen(const bf16* __restrict__ out_h,
                                             const bf16* __restrict__ Wgen16,
                                             const float* __restrict__ b_gen,
                                             float* __restrict__ out) {
  __shared__ bf16 As[4 * 4096];
  __shared__ bf16 Bs[4 * 4096];
  const int tid = threadIdx.x;
  const int m0 = blockIdx.x * 128;
  const int r0 = tid >> 2, k0 = (tid & 3) * 8;
  const bf16* aRow0 = out_h + (size_t)(m0 + r0) * 512 + k0;
  const bf16* aRow1 = out_h + (size_t)(m0 + r0 + 64) * 512 + k0;
  const bf16* bRow0 = Wgen16 + (size_t)r0 * 512 + k0;
  const bf16* bRow1 = Wgen16 + (size_t)(r0 + 64) * 512 + k0;
  v4f acc[4][4];
  zero_acc(acc);
  mm_qb32<512>(aRow0, aRow1, bRow0, bRow1, As, Bs, tid, acc);
  const int wave = tid >> 6, lane = tid & 63;
  const int wr = (wave >> 1) * 64, wc = (wave & 1) * 64;
  const int fr = lane & 15, fq = lane >> 4;
#pragma unroll
  for (int i = 0; i < 4; ++i) {
#pragma unroll
    for (int j = 0; j < 4; ++j) {
      int col = wc + j * 16 + fr;
      if (col < C_) {
        float bg = b_gen[col];
#pragma unroll
        for (int r = 0; r < 4; ++r) {
          int row = m0 + wr + i * 16 + fq * 4 + r;
          out[(size_t)row * C_ + col] = acc[i][j][r] + bg;
        }
      }
    }
  }
}

// ---------------------------------------------------------------- launch
extern "C" void kernel_launch(void* const* d_in, const int* in_sizes, int n_in,
                              void* d_out, int out_size, void* d_ws, size_t ws_size,
                              hipStream_t stream) {
  (void)in_sizes; (void)n_in; (void)out_size;
  const float* batch_H = (const float*)d_in[0];
  const int*   text    = (const int*)d_in[1];
  const float* W_feat  = (const float*)d_in[2];
  const float* W_hid   = (const float*)d_in[3];
  const float* b_hid   = (const float*)d_in[4];
  const float* w_score = (const float*)d_in[5];
  const float* W_ih    = (const float*)d_in[6];
  const float* W_hh    = (const float*)d_in[7];
  const float* b_ih    = (const float*)d_in[8];
  const float* b_hh    = (const float*)d_in[9];
  const float* W_gen   = (const float*)d_in[10];
  const float* b_gen   = (const float*)d_in[11];
  float* out = (float*)d_out;

  char* ws = (char*)d_ws;
  bf16*  F       = (bf16*)(ws);                  // 67108864
  bf16*  out_h   = (bf16*)(ws + 67108864);       // 13631488
  float* P       = (float*)(ws + 80740352);      // 1048576
  bf16*  xb0     = (bf16*)(ws + 81788928);       // 1048576
  bf16*  xb1     = (bf16*)(ws + 82837504);       // 1048576
  float* c_state = (float*)(ws + 83886080);      // 1048576
  bf16*  Wcat    = (bf16*)(ws + 84934656);       // 4194304
  bf16*  Wf16    = (bf16*)(ws + 89128960);       // 524288
  bf16*  Whid16  = (bf16*)(ws + 89653248);       // 524288
  bf16*  Wgen16  = (bf16*)(ws + 90177536);       // 131072
  float* OHT     = (float*)(ws + 90308608);      // 794624 (pad to 1048576)
  bf16*  bH16    = (bf16*)(ws + 91357184);       // 67108864 -> total 158466048
  const bool useBH16 = (ws_size >= (size_t)158466048);

  bf16* xb[2] = {xb0, xb1};

  hipMemsetAsync(xb0, 0, (size_t)512 * 1024 * 2, stream);
  hipMemsetAsync(c_state, 0, (size_t)512 * 512 * 4, stream);

  const int nbhb = useBH16 ? 16384 : 0;  // bH16 cvt blocks (8 elems/thread)
  k_prep_all<<<dim3(2440 + nbhb), 256, 0, stream>>>(
      batch_H, bH16, nbhb, W_feat, Wf16, W_hid, Whid16,
      W_ih, W_hh, Wcat, W_gen, Wgen16, OHT);

  if (useBH16) {
    k_feat16<<<dim3(512, 4), 256, 0, stream>>>(bH16, Wf16, F);
  } else {
    k_feat32<<<dim3(512, 4), 256, 0, stream>>>(batch_H, Wf16, F);
  }

  for (int s = 0; s < S_; ++s) {
    bf16* cur = xb[s & 1];
    bf16* nxt = xb[(s + 1) & 1];
    k_hp<<<dim3(128), 256, 0, stream>>>(cur, Whid16, b_hid, P);
    if (useBH16) {
      k_attn<true><<<dim3(512), 512, 0, stream>>>(F, P, w_score, bH16, cur);
    } else {
      k_attn<false><<<dim3(512), 512, 0, stream>>>(F, P, w_score, batch_H, cur);
    }
    k_gates<<<dim3(256), 256, 0, stream>>>(cur, Wcat, OHT, b_ih, b_hh, text,
                                           c_state, out_h, nxt, s);
  }
  k_gen<<<dim3(104, 1), 256, 0, stream>>>(out_h, Wgen16, b_gen, out);
}